// Round 6
// baseline (193.423 us; speedup 1.0000x reference)
//
#include <hip/hip_runtime.h>

static constexpr int    N      = 2048;
static constexpr int    NBLK   = 256;
static constexpr int    NTHR   = 1024;
static constexpr int    RPB    = 8;     // rows per block
static constexpr double D_MASS = 0.9;
static constexpr double D_TOL  = 0.01;
static constexpr int    NITER  = 50;

typedef _Float16 half4_t __attribute__((ext_vector_type(4)));
typedef _Float16 half2_t __attribute__((ext_vector_type(2)));

struct Ws {
    unsigned flag0[NBLK], flagP[NBLK], flagV[NBLK], flagE[NBLK];  // epoch slots
    double bandSum[NBLK], dotParts[NBLK], errParts[NBLK];
    float  V[N], Vp[N];
    float  partialT[NBLK * N];            // 2 MB column partials
};

__global__ void init_flags(Ws* ws) {
    const int t = threadIdx.x;            // 256 threads
    ws->flag0[t] = 0u; ws->flagP[t] = 0u; ws->flagV[t] = 0u; ws->flagE[t] = 0u;
}

// deterministic all-thread block reduction (1024 threads, 16 waves)
__device__ __forceinline__ double block_reduce(double v, double* s16) {
    for (int off = 32; off; off >>= 1) v += __shfl_xor(v, off, 64);
    const int wave = threadIdx.x >> 6, lane = threadIdx.x & 63;
    __syncthreads();                 // protect s16 reuse
    if (lane == 0) s16[wave] = v;
    __syncthreads();
    double s = 0.0;
    #pragma unroll
    for (int w = 0; w < 16; ++w) s += s16[w];
    return s;
}

// distributed barrier: release-store own epoch slot; poll all slots in parallel
__device__ __forceinline__ void arrive(unsigned* slot, unsigned epoch) {
    __syncthreads();   // all block stores drained (vmcnt) before release store
    if (threadIdx.x == 0)
        __hip_atomic_store(slot, epoch, __ATOMIC_RELEASE, __HIP_MEMORY_SCOPE_AGENT);
}
__device__ __forceinline__ void wait_all(unsigned* arr, unsigned epoch) {
    if (threadIdx.x < NBLK) {
        while (__hip_atomic_load(arr + threadIdx.x, __ATOMIC_RELAXED,
                                 __HIP_MEMORY_SCOPE_AGENT) < epoch)
            __builtin_amdgcn_s_sleep(1);
    }
    __syncthreads();
    __builtin_amdgcn_fence(__ATOMIC_ACQUIRE, "agent");
}

__global__ void __launch_bounds__(NTHR, 1)
epot_kernel(const float* __restrict__ C, const float* __restrict__ a,
            const float* __restrict__ b, float* __restrict__ K,
            Ws* __restrict__ ws)
{
    __shared__ _Float16 band[RPB][N];        // 32 KB: this block's K0 band (fp16)
    __shared__ double s16[16];
    __shared__ double swred[16][RPB];        // 1 KB column-reduce scratch
    __shared__ double sU[RPB], sUp[RPB], sRowPrev[RPB], sRowSum[RPB];
    __shared__ double sVown[RPB], sColPrev[RPB], sAn[RPB], sBn[RPB];

    const int tid  = threadIdx.x;
    const int bid  = blockIdx.x;
    const int lane = tid & 63;
    const int r0   = bid * RPB;
    const int rloc = tid >> 7;               // 0..7 row in band (128 thr/row)
    const int cgrp = tid & 127;              // col group within row

    // ---- phase 0: a/b sums (redundant per block), band = fp16(exp(-10C)) ----
    const double a_sum = block_reduce((double)a[tid] + (double)a[tid + 1024], s16);
    const double b_sum = block_reduce((double)b[tid] + (double)b[tid + 1024], s16);

    {
        const int i = r0 + rloc;
        const float4* c4 = (const float4*)(C + (size_t)i * N);
        double s = 0.0;
        #pragma unroll 4
        for (int j4 = cgrp; j4 < N / 4; j4 += 128) {
            float4 c = c4[j4];
            half4_t h;
            h[0] = (_Float16)expf(-10.0f * c.x);
            h[1] = (_Float16)expf(-10.0f * c.y);
            h[2] = (_Float16)expf(-10.0f * c.z);
            h[3] = (_Float16)expf(-10.0f * c.w);
            *(half4_t*)&band[rloc][4 * j4] = h;
            s += (double)(float)h[0] + (double)(float)h[1]
               + (double)(float)h[2] + (double)(float)h[3];
        }
        for (int off = 32; off; off >>= 1) s += __shfl_xor(s, off, 64);
        __syncthreads();                      // s16 free (b_sum readers done)
        if (lane == 0) s16[tid >> 6] = s;     // 2 waves per row
        __syncthreads();
        if (tid < RPB) {
            sRowSum[tid]  = s16[2 * tid] + s16[2 * tid + 1];
            sU[tid] = 1.0; sRowPrev[tid] = 1.0; sUp[tid] = 1.0;
            sVown[tid] = 1.0; sColPrev[tid] = 1.0;
            sAn[tid] = (double)a[r0 + tid] / a_sum;
            sBn[tid] = (double)b[r0 + tid] / b_sum;
        }
        __syncthreads();
        if (tid == 0) {
            double bs = 0.0;
            #pragma unroll
            for (int r = 0; r < RPB; ++r) bs += sRowSum[r];
            ws->bandSum[bid] = bs;
        }
    }
    arrive(&ws->flag0[bid], 1u);
    wait_all(ws->flag0, 1u);
    const double k0sum = block_reduce((tid < NBLK) ? ws->bandSum[tid] : 0.0, s16);

    double W = D_MASS / k0sum;   // K_t = U[i]*K0[i,j]*V[j]*W
    double Wp = 0.0;
    bool done = false;

    for (int cpt = 0; cpt < NITER && !done; ++cpt) {
        const bool erriter = (cpt % 10) == 0;

        if (cpt > 0) {   // consume previous iteration's dot -> mass scaling
            wait_all(ws->flagV, (unsigned)cpt);
            const double sd = block_reduce((tid < NBLK) ? ws->dotParts[tid] : 0.0, s16);
            W = D_MASS / sd;
        }
        if (erriter) {
            Wp = W;
            if (tid < RPB) sUp[tid] = sU[tid];
        }
        __syncthreads();

        // ---- A1: row sums (band x V) + row scaling ----
        if (cpt == 0) {
            if (tid < RPB) {
                const double Uq = sU[tid] / sRowPrev[tid];
                double r = sAn[tid] / (Uq * W * sRowSum[tid]);
                if (r > 1.0) r = 1.0;
                sU[tid] = Uq * r; sRowPrev[tid] = r;
            }
        } else {
            const float4* v4 = (const float4*)ws->V;
            double s = 0.0;
            #pragma unroll 4
            for (int j4 = cgrp; j4 < N / 4; j4 += 128) {
                half4_t h = *(const half4_t*)&band[rloc][4 * j4];
                float4 vv = v4[j4];
                s += (double)((float)h[0] * vv.x) + (double)((float)h[1] * vv.y)
                   + (double)((float)h[2] * vv.z) + (double)((float)h[3] * vv.w);
            }
            for (int off = 32; off; off >>= 1) s += __shfl_xor(s, off, 64);
            __syncthreads();
            if (lane == 0) s16[tid >> 6] = s;
            __syncthreads();
            if (tid < RPB) {
                const double Uq = sU[tid] / sRowPrev[tid];
                double r = sAn[tid] / (Uq * W * (s16[2 * tid] + s16[2 * tid + 1]));
                if (r > 1.0) r = 1.0;
                sU[tid] = Uq * r; sRowPrev[tid] = r;
            }
        }
        __syncthreads();

        // ---- A2: column partials over band with new U ----
        {
            double ub[RPB];
            #pragma unroll
            for (int r = 0; r < RPB; ++r) ub[r] = sU[r];
            const int j0 = 2 * tid;
            double ax = 0.0, ay = 0.0;
            #pragma unroll
            for (int r = 0; r < RPB; ++r) {
                half2_t hv = *(const half2_t*)&band[r][j0];
                ax += (double)(float)hv[0] * ub[r];
                ay += (double)(float)hv[1] * ub[r];
            }
            float2 o; o.x = (float)ax; o.y = (float)ay;
            *(float2*)(ws->partialT + (size_t)bid * N + j0) = o;
        }
        arrive(&ws->flagP[bid], (unsigned)(cpt + 1));
        wait_all(ws->flagP, (unsigned)(cpt + 1));

        // ---- B: own 8 columns -> T_j, col scaling, V, dot partial ----
        {
            const int g = tid >> 3, jj = tid & 7;
            const int j = r0 + jj;
            double v = (double)ws->partialT[(size_t)g * N + j]
                     + (double)ws->partialT[(size_t)(g + 128) * N + j];
            v += __shfl_xor(v, 8, 64);       // fold the 8 g-values in this wave
            v += __shfl_xor(v, 16, 64);
            v += __shfl_xor(v, 32, 64);
            if (lane < 8) swred[tid >> 6][lane] = v;
            __syncthreads();
            if (tid < RPB) {
                double Tj = 0.0;
                #pragma unroll
                for (int w = 0; w < 16; ++w) Tj += swred[w][tid];
                const double Vq = sVown[tid] / sColPrev[tid];
                double cf = sBn[tid] / (Vq * W * Tj);
                if (cf > 1.0) cf = 1.0;
                if (erriter) ws->Vp[r0 + tid] = (float)sVown[tid];
                const double Vn = Vq * cf;
                sVown[tid] = Vn; sColPrev[tid] = cf;
                ws->V[r0 + tid] = (float)Vn;
                swred[0][tid] = Tj * Vn;      // reuse as dot scratch
            }
            __syncthreads();
            if (tid == 0) {
                double d = 0.0;
                #pragma unroll
                for (int q = 0; q < RPB; ++q) d += swred[0][q];
                ws->dotParts[bid] = d;
            }
        }
        arrive(&ws->flagV[bid], (unsigned)(cpt + 1));

        // ---- err check (every 10 iters), then speculative output write ----
        if (erriter) {
            wait_all(ws->flagV, (unsigned)(cpt + 1));
            const double sd = block_reduce((tid < NBLK) ? ws->dotParts[tid] : 0.0, s16);
            const double Wn = D_MASS / sd;
            const int i = r0 + rloc;
            const double upw = sUp[rloc] * Wp;
            const double unw = sU[rloc] * Wn;
            const float4* vp4 = (const float4*)ws->Vp;
            const float4* vn4 = (const float4*)ws->V;
            float4* k4 = (float4*)(K + (size_t)i * N);
            // pass 1: error partials only (no global stores -> cheap drain)
            double e2 = 0.0;
            #pragma unroll 4
            for (int j4 = cgrp; j4 < N / 4; j4 += 128) {
                half4_t h = *(const half4_t*)&band[rloc][4 * j4];
                float4 vp = vp4[j4], vn = vn4[j4];
                double d;
                d = (double)(float)h[0] * (upw * (double)vp.x - unw * (double)vn.x); e2 += d * d;
                d = (double)(float)h[1] * (upw * (double)vp.y - unw * (double)vn.y); e2 += d * d;
                d = (double)(float)h[2] * (upw * (double)vp.z - unw * (double)vn.z); e2 += d * d;
                d = (double)(float)h[3] * (upw * (double)vp.w - unw * (double)vn.w); e2 += d * d;
            }
            const double be = block_reduce(e2, s16);
            if (tid == 0) ws->errParts[bid] = be;
            arrive(&ws->flagE[bid], (unsigned)(cpt / 10 + 1));
            // pass 2: speculative output write overlaps flag propagation
            #pragma unroll 4
            for (int j4 = cgrp; j4 < N / 4; j4 += 128) {
                half4_t h = *(const half4_t*)&band[rloc][4 * j4];
                float4 vn = vn4[j4];
                float4 kn;
                kn.x = (float)(unw * (double)(float)h[0] * (double)vn.x);
                kn.y = (float)(unw * (double)(float)h[1] * (double)vn.y);
                kn.z = (float)(unw * (double)(float)h[2] * (double)vn.z);
                kn.w = (float)(unw * (double)(float)h[3] * (double)vn.w);
                k4[j4] = kn;
            }
            wait_all(ws->flagE, (unsigned)(cpt / 10 + 1));
            const double te = block_reduce((tid < NBLK) ? ws->errParts[tid] : 0.0, s16);
            done = (sqrt(te) <= D_TOL);       // bitwise-identical everywhere
        }
    }

    // ---- only if never converged: final output write ----
    if (!done) {
        wait_all(ws->flagV, (unsigned)NITER);
        const double sd = block_reduce((tid < NBLK) ? ws->dotParts[tid] : 0.0, s16);
        const double Wf = D_MASS / sd;
        const int i = r0 + rloc;
        const double uf = sU[rloc] * Wf;
        const float4* vn4 = (const float4*)ws->V;
        float4* k4 = (float4*)(K + (size_t)i * N);
        #pragma unroll 4
        for (int j4 = cgrp; j4 < N / 4; j4 += 128) {
            half4_t h = *(const half4_t*)&band[rloc][4 * j4];
            float4 vv = vn4[j4];
            float4 o;
            o.x = (float)(uf * (double)(float)h[0] * (double)vv.x);
            o.y = (float)(uf * (double)(float)h[1] * (double)vv.y);
            o.z = (float)(uf * (double)(float)h[2] * (double)vv.z);
            o.w = (float)(uf * (double)(float)h[3] * (double)vv.w);
            k4[j4] = o;
        }
    }
}

extern "C" void kernel_launch(void* const* d_in, const int* in_sizes, int n_in,
                              void* d_out, int out_size, void* d_ws, size_t ws_size,
                              hipStream_t stream) {
    const float* C = (const float*)d_in[0];
    const float* a = (const float*)d_in[1];
    const float* b = (const float*)d_in[2];
    float* K = (float*)d_out;
    Ws*    w = (Ws*)d_ws;
    init_flags<<<1, NBLK, 0, stream>>>(w);
    void* args[5] = { (void*)&C, (void*)&a, (void*)&b, (void*)&K, (void*)&w };
    (void)hipLaunchCooperativeKernel((const void*)epot_kernel, dim3(NBLK), dim3(NTHR),
                                     args, 0, stream);
}

// Round 7
// 58.011 us; speedup vs baseline: 3.3343x; 3.3343x over previous
//
#include <hip/hip_runtime.h>

static constexpr int    N      = 2048;
static constexpr int    NBLK   = 256;
static constexpr int    NTHR   = 1024;
static constexpr int    RPB    = 8;     // rows (or cols) per block
static constexpr double D_MASS = 0.9;
static constexpr double D_TOL  = 0.01;
static constexpr int    NITER  = 50;

typedef _Float16 half4_t __attribute__((ext_vector_type(4)));
typedef _Float16 half2_t __attribute__((ext_vector_type(2)));

struct Ws {
    unsigned cntP, cntV, cntE, _pad;     // counters for K5 only (zeroed by K1)
    double a_sum, b_sum;
    double bandSum[NBLK];
    double rowSum[N];
    double dotParts[NBLK];
    double errParts[NBLK];
    float  U[N], row_prev[N], V[N], col_prev[N], Vp[N];
    float  partialT[(size_t)N * NBLK];   // [col][srcblk], 2 MB
};

// deterministic all-thread block reduction (1024 threads, 16 waves)
__device__ __forceinline__ double block_reduce(double v, double* s16) {
    for (int off = 32; off; off >>= 1) v += __shfl_xor(v, off, 64);
    const int wave = threadIdx.x >> 6, lane = threadIdx.x & 63;
    __syncthreads();
    if (lane == 0) s16[wave] = v;
    __syncthreads();
    double s = 0.0;
    #pragma unroll
    for (int w = 0; w < 16; ++w) s += s16[w];
    return s;
}

// counter-based exchange (K5 only; proven in round 5)
__device__ __forceinline__ void arrive(unsigned* cnt) {
    __syncthreads();
    if (threadIdx.x == 0)
        __hip_atomic_fetch_add(cnt, 1u, __ATOMIC_RELEASE, __HIP_MEMORY_SCOPE_AGENT);
}
__device__ __forceinline__ void wait_cnt(unsigned* cnt, unsigned target) {
    if (threadIdx.x == 0) {
        while (__hip_atomic_load(cnt, __ATOMIC_RELAXED, __HIP_MEMORY_SCOPE_AGENT) < target)
            __builtin_amdgcn_s_sleep(2);
        __builtin_amdgcn_fence(__ATOMIC_ACQUIRE, "agent");
    }
    __syncthreads();
}

// ---- K1: row sums of K0 = exp(-10C), band sums, a/b sums, zero counters ----
__global__ void __launch_bounds__(NTHR)
k1_sums(const float* __restrict__ C, const float* __restrict__ a,
        const float* __restrict__ b, Ws* __restrict__ ws)
{
    __shared__ double s16[16];
    const int tid = threadIdx.x, bid = blockIdx.x, lane = tid & 63;
    const int r0 = bid * RPB, rloc = tid >> 7, cgrp = tid & 127;

    if (bid == 0 && tid == 0) { ws->cntP = 0u; ws->cntV = 0u; ws->cntE = 0u; }
    if (bid == 0) {
        double t = block_reduce((double)a[tid] + (double)a[tid + 1024], s16);
        if (tid == 0) ws->a_sum = t;
    } else if (bid == 1) {
        double t = block_reduce((double)b[tid] + (double)b[tid + 1024], s16);
        if (tid == 0) ws->b_sum = t;
    }

    const int i = r0 + rloc;
    const float4* c4 = (const float4*)(C + (size_t)i * N);
    double s = 0.0;
    #pragma unroll 4
    for (int j4 = cgrp; j4 < N / 4; j4 += 128) {
        float4 c = c4[j4];
        s += (double)expf(-10.0f * c.x) + (double)expf(-10.0f * c.y)
           + (double)expf(-10.0f * c.z) + (double)expf(-10.0f * c.w);
    }
    for (int off = 32; off; off >>= 1) s += __shfl_xor(s, off, 64);
    __syncthreads();                     // s16 free (block_reduce readers done)
    if (lane == 0) s16[tid >> 6] = s;    // 2 waves per row
    __syncthreads();
    if (tid < RPB) ws->rowSum[r0 + tid] = s16[2 * tid] + s16[2 * tid + 1];
    if (tid == 0) {
        double bs = 0.0;
        #pragma unroll
        for (int w = 0; w < 16; ++w) bs += s16[w];
        ws->bandSum[bid] = bs;
    }
}

// ---- K2: iter-0 row scaling (U'), column partials [col][srcblk] ----
__global__ void __launch_bounds__(NTHR)
k2_rowscale_colpart(const float* __restrict__ C, const float* __restrict__ a,
                    Ws* __restrict__ ws)
{
    __shared__ double s16[16];
    __shared__ double sU[RPB];
    const int tid = threadIdx.x, bid = blockIdx.x;
    const int r0 = bid * RPB;

    const double k0sum = block_reduce((tid < NBLK) ? ws->bandSum[tid] : 0.0, s16);
    const double W0 = D_MASS / k0sum;

    if (tid < RPB) {
        const int i = r0 + tid;
        double r = ((double)a[i] / ws->a_sum) / (W0 * ws->rowSum[i]);
        if (r > 1.0) r = 1.0;
        sU[tid] = r;
        ws->U[i] = (float)r;
        ws->row_prev[i] = (float)r;
    }
    __syncthreads();

    double ub[RPB];
    #pragma unroll
    for (int r = 0; r < RPB; ++r) ub[r] = sU[r];
    const int j0 = 2 * tid;
    double ax = 0.0, ay = 0.0;
    #pragma unroll
    for (int r = 0; r < RPB; ++r) {
        const float2 c = *(const float2*)(C + (size_t)(r0 + r) * N + j0);
        ax += (double)expf(-10.0f * c.x) * ub[r];
        ay += (double)expf(-10.0f * c.y) * ub[r];
    }
    ws->partialT[(size_t)j0 * NBLK + bid]       = (float)ax;
    ws->partialT[(size_t)(j0 + 1) * NBLK + bid] = (float)ay;
}

// ---- K3: column reduce (coalesced), col scaling, V, dot partials ----
__global__ void __launch_bounds__(256)
k3_colscale(const float* __restrict__ b, Ws* __restrict__ ws)
{
    __shared__ double s4[4];
    __shared__ double sT[RPB], sD[RPB];
    const int tid = threadIdx.x, bid = blockIdx.x;

    double v = (double)ws->bandSum[tid];     // 256 values, one per thread
    for (int off = 32; off; off >>= 1) v += __shfl_xor(v, off, 64);
    if ((tid & 63) == 0) s4[tid >> 6] = v;
    __syncthreads();
    const double W0 = D_MASS / (s4[0] + s4[1] + s4[2] + s4[3]);

    const int jj = tid >> 5, p = tid & 31;   // 32 threads per column
    const int j = bid * RPB + jj;
    double t = 0.0;
    #pragma unroll
    for (int q = 0; q < 8; ++q)
        t += (double)ws->partialT[(size_t)j * NBLK + p + 32 * q];
    for (int off = 16; off; off >>= 1) t += __shfl_xor(t, off, 64);
    if (p == 0) sT[jj] = t;
    __syncthreads();

    if (tid < RPB) {
        const int jc = bid * RPB + tid;
        const double Tj = sT[tid];
        double cf = ((double)b[jc] / ws->b_sum) / (W0 * Tj);   // Vq = 1
        if (cf > 1.0) cf = 1.0;
        ws->V[jc] = (float)cf;
        ws->col_prev[jc] = (float)cf;
        sD[tid] = Tj * cf;
    }
    __syncthreads();
    if (tid == 0) {
        double d = 0.0;
        #pragma unroll
        for (int q = 0; q < RPB; ++q) d += sD[q];
        ws->dotParts[bid] = d;
    }
}

// ---- K4: Wn, fused err^2 partials + speculative output (fp32 exp) ----
__global__ void __launch_bounds__(NTHR)
k4_err_out(const float* __restrict__ C, float* __restrict__ K, Ws* __restrict__ ws)
{
    __shared__ double s16[16];
    const int tid = threadIdx.x, bid = blockIdx.x;
    const int r0 = bid * RPB, rloc = tid >> 7, cgrp = tid & 127;

    const double sd = block_reduce((tid < NBLK) ? ws->dotParts[tid] : 0.0, s16);
    const double Wn = D_MASS / sd;
    const double k0sum = block_reduce((tid < NBLK) ? ws->bandSum[tid] : 0.0, s16);
    const double upw = D_MASS / k0sum;       // Up=1, vp=1, Wp=W0

    const int i = r0 + rloc;
    const double unw = Wn * (double)ws->U[i];
    const float4* c4  = (const float4*)(C + (size_t)i * N);
    const float4* vn4 = (const float4*)ws->V;
    float4* k4p = (float4*)(K + (size_t)i * N);
    double e2 = 0.0;
    #pragma unroll 4
    for (int j4 = cgrp; j4 < N / 4; j4 += 128) {
        float4 c = c4[j4], vn = vn4[j4];
        const double k0x = (double)expf(-10.0f * c.x);
        const double k0y = (double)expf(-10.0f * c.y);
        const double k0z = (double)expf(-10.0f * c.z);
        const double k0w = (double)expf(-10.0f * c.w);
        float4 kn;
        kn.x = (float)(unw * k0x * (double)vn.x);
        kn.y = (float)(unw * k0y * (double)vn.y);
        kn.z = (float)(unw * k0z * (double)vn.z);
        kn.w = (float)(unw * k0w * (double)vn.w);
        k4p[j4] = kn;                        // speculative final output (iter-0 Kn)
        double d;
        d = k0x * (upw - unw * (double)vn.x); e2 += d * d;
        d = k0y * (upw - unw * (double)vn.y); e2 += d * d;
        d = k0z * (upw - unw * (double)vn.z); e2 += d * d;
        d = k0w * (upw - unw * (double)vn.w); e2 += d * d;
    }
    const double be = block_reduce(e2, s16);
    if (tid == 0) ws->errParts[bid] = be;
}

// ---- K5: cooperative; exit if converged at iter 0, else run iters 1..49 ----
__global__ void __launch_bounds__(NTHR, 1)
k5_iters(const float* __restrict__ C, const float* __restrict__ a,
         const float* __restrict__ b, float* __restrict__ K, Ws* __restrict__ ws)
{
    __shared__ _Float16 band[RPB][N];        // 32 KB fp16 K0 band
    __shared__ double s16[16];
    __shared__ double sU[RPB], sUp[RPB], sRowPrev[RPB];
    __shared__ double sVown[RPB], sColPrev[RPB], sAn[RPB], sBn[RPB], sDot[RPB];

    const int tid = threadIdx.x, bid = blockIdx.x, lane = tid & 63;
    const int r0 = bid * RPB, rloc = tid >> 7, cgrp = tid & 127;

    // early-exit: iter-0 error
    const double te0 = block_reduce((tid < NBLK) ? ws->errParts[tid] : 0.0, s16);
    if (sqrt(te0) <= D_TOL) return;          // converged: K4's output stands

    // load state from iter 0
    if (tid < RPB) {
        sU[tid] = (double)ws->U[r0 + tid];
        sRowPrev[tid] = (double)ws->row_prev[r0 + tid];
        sVown[tid] = (double)ws->V[r0 + tid];
        sColPrev[tid] = (double)ws->col_prev[r0 + tid];
        sAn[tid] = (double)a[r0 + tid] / ws->a_sum;
        sBn[tid] = (double)b[r0 + tid] / ws->b_sum;
        sUp[tid] = 1.0;
    }
    {   // rebuild band
        const int i = r0 + rloc;
        const float4* c4 = (const float4*)(C + (size_t)i * N);
        #pragma unroll 4
        for (int j4 = cgrp; j4 < N / 4; j4 += 128) {
            float4 c = c4[j4];
            half4_t h;
            h[0] = (_Float16)expf(-10.0f * c.x);
            h[1] = (_Float16)expf(-10.0f * c.y);
            h[2] = (_Float16)expf(-10.0f * c.z);
            h[3] = (_Float16)expf(-10.0f * c.w);
            *(half4_t*)&band[rloc][4 * j4] = h;
        }
    }
    __syncthreads();

    double W = 0.0, Wp = 0.0;
    bool done = false;

    for (int cpt = 1; cpt < NITER && !done; ++cpt) {
        const bool erriter = (cpt % 10) == 0;

        if (cpt > 1) wait_cnt(&ws->cntV, (unsigned)(NBLK * (cpt - 1)));
        W = D_MASS / block_reduce((tid < NBLK) ? ws->dotParts[tid] : 0.0, s16);
        if (erriter) {
            Wp = W;
            if (tid < RPB) sUp[tid] = sU[tid];
        }
        __syncthreads();

        // A1: row sums (band x V) + row scaling
        {
            const float4* v4 = (const float4*)ws->V;
            double s = 0.0;
            #pragma unroll 4
            for (int j4 = cgrp; j4 < N / 4; j4 += 128) {
                half4_t h = *(const half4_t*)&band[rloc][4 * j4];
                float4 vv = v4[j4];
                s += (double)((float)h[0] * vv.x) + (double)((float)h[1] * vv.y)
                   + (double)((float)h[2] * vv.z) + (double)((float)h[3] * vv.w);
            }
            for (int off = 32; off; off >>= 1) s += __shfl_xor(s, off, 64);
            __syncthreads();
            if (lane == 0) s16[tid >> 6] = s;
            __syncthreads();
            if (tid < RPB) {
                const double Uq = sU[tid] / sRowPrev[tid];
                double r = sAn[tid] / (Uq * W * (s16[2 * tid] + s16[2 * tid + 1]));
                if (r > 1.0) r = 1.0;
                sU[tid] = Uq * r; sRowPrev[tid] = r;
            }
        }
        __syncthreads();

        // A2: column partials -> [col][srcblk]
        {
            double ub[RPB];
            #pragma unroll
            for (int r = 0; r < RPB; ++r) ub[r] = sU[r];
            const int j0 = 2 * tid;
            double ax = 0.0, ay = 0.0;
            #pragma unroll
            for (int r = 0; r < RPB; ++r) {
                half2_t hv = *(const half2_t*)&band[r][j0];
                ax += (double)(float)hv[0] * ub[r];
                ay += (double)(float)hv[1] * ub[r];
            }
            ws->partialT[(size_t)j0 * NBLK + bid]       = (float)ax;
            ws->partialT[(size_t)(j0 + 1) * NBLK + bid] = (float)ay;
        }
        arrive(&ws->cntP);
        wait_cnt(&ws->cntP, (unsigned)(NBLK * cpt));

        // B: own 8 columns (coalesced), col scaling, V, dot partial
        {
            const int jj = tid >> 7, p = tid & 127;
            const int j = r0 + jj;
            double t = (double)ws->partialT[(size_t)j * NBLK + p]
                     + (double)ws->partialT[(size_t)j * NBLK + 128 + p];
            for (int off = 32; off; off >>= 1) t += __shfl_xor(t, off, 64);
            __syncthreads();
            if (lane == 0) s16[tid >> 6] = t;
            __syncthreads();
            if (tid < RPB) {
                const double Tj = s16[2 * tid] + s16[2 * tid + 1];
                const double Vq = sVown[tid] / sColPrev[tid];
                double cf = sBn[tid] / (Vq * W * Tj);
                if (cf > 1.0) cf = 1.0;
                if (erriter) ws->Vp[r0 + tid] = (float)sVown[tid];
                const double Vn = Vq * cf;
                sVown[tid] = Vn; sColPrev[tid] = cf;
                ws->V[r0 + tid] = (float)Vn;
                sDot[tid] = Tj * Vn;
            }
            __syncthreads();
            if (tid == 0) {
                double d = 0.0;
                #pragma unroll
                for (int q = 0; q < RPB; ++q) d += sDot[q];
                ws->dotParts[bid] = d;
            }
        }
        arrive(&ws->cntV);

        // err check + speculative output (every 10 iters)
        if (erriter) {
            wait_cnt(&ws->cntV, (unsigned)(NBLK * cpt));
            const double sd = block_reduce((tid < NBLK) ? ws->dotParts[tid] : 0.0, s16);
            const double Wn = D_MASS / sd;
            const int i = r0 + rloc;
            const double upw = sUp[rloc] * Wp;
            const double unw = sU[rloc] * Wn;
            const float4* vp4 = (const float4*)ws->Vp;
            const float4* vn4 = (const float4*)ws->V;
            float4* k4p = (float4*)(K + (size_t)i * N);
            double e2 = 0.0;
            #pragma unroll 4
            for (int j4 = cgrp; j4 < N / 4; j4 += 128) {
                half4_t h = *(const half4_t*)&band[rloc][4 * j4];
                float4 vp = vp4[j4], vn = vn4[j4];
                double d;
                d = (double)(float)h[0] * (upw * (double)vp.x - unw * (double)vn.x); e2 += d * d;
                d = (double)(float)h[1] * (upw * (double)vp.y - unw * (double)vn.y); e2 += d * d;
                d = (double)(float)h[2] * (upw * (double)vp.z - unw * (double)vn.z); e2 += d * d;
                d = (double)(float)h[3] * (upw * (double)vp.w - unw * (double)vn.w); e2 += d * d;
            }
            const double be = block_reduce(e2, s16);
            if (tid == 0) ws->errParts[bid] = be;
            arrive(&ws->cntE);
            // speculative output overlaps flag propagation
            #pragma unroll 4
            for (int j4 = cgrp; j4 < N / 4; j4 += 128) {
                half4_t h = *(const half4_t*)&band[rloc][4 * j4];
                float4 vn = vn4[j4];
                float4 kn;
                kn.x = (float)(unw * (double)(float)h[0] * (double)vn.x);
                kn.y = (float)(unw * (double)(float)h[1] * (double)vn.y);
                kn.z = (float)(unw * (double)(float)h[2] * (double)vn.z);
                kn.w = (float)(unw * (double)(float)h[3] * (double)vn.w);
                k4p[j4] = kn;
            }
            wait_cnt(&ws->cntE, (unsigned)(NBLK * (cpt / 10)));
            const double te = block_reduce((tid < NBLK) ? ws->errParts[tid] : 0.0, s16);
            done = (sqrt(te) <= D_TOL);      // bitwise-identical everywhere
        }
    }

    if (!done) {   // ran out of iterations: final output from current state
        wait_cnt(&ws->cntV, (unsigned)(NBLK * (NITER - 1)));
        const double sd = block_reduce((tid < NBLK) ? ws->dotParts[tid] : 0.0, s16);
        const double Wf = D_MASS / sd;
        const int i = r0 + rloc;
        const double uf = sU[rloc] * Wf;
        const float4* vn4 = (const float4*)ws->V;
        float4* k4p = (float4*)(K + (size_t)i * N);
        #pragma unroll 4
        for (int j4 = cgrp; j4 < N / 4; j4 += 128) {
            half4_t h = *(const half4_t*)&band[rloc][4 * j4];
            float4 vv = vn4[j4];
            float4 o;
            o.x = (float)(uf * (double)(float)h[0] * (double)vv.x);
            o.y = (float)(uf * (double)(float)h[1] * (double)vv.y);
            o.z = (float)(uf * (double)(float)h[2] * (double)vv.z);
            o.w = (float)(uf * (double)(float)h[3] * (double)vv.w);
            k4p[j4] = o;
        }
    }
}

extern "C" void kernel_launch(void* const* d_in, const int* in_sizes, int n_in,
                              void* d_out, int out_size, void* d_ws, size_t ws_size,
                              hipStream_t stream) {
    const float* C = (const float*)d_in[0];
    const float* a = (const float*)d_in[1];
    const float* b = (const float*)d_in[2];
    float* K = (float*)d_out;
    Ws*    w = (Ws*)d_ws;

    k1_sums<<<NBLK, NTHR, 0, stream>>>(C, a, b, w);
    k2_rowscale_colpart<<<NBLK, NTHR, 0, stream>>>(C, a, w);
    k3_colscale<<<NBLK, 256, 0, stream>>>(b, w);
    k4_err_out<<<NBLK, NTHR, 0, stream>>>(C, K, w);
    void* args[5] = { (void*)&C, (void*)&a, (void*)&b, (void*)&K, (void*)&w };
    (void)hipLaunchCooperativeKernel((const void*)k5_iters, dim3(NBLK), dim3(NTHR),
                                     args, 0, stream);
}